// Round 8
// baseline (333.477 us; speedup 1.0000x reference)
//
#include <hip/hip_runtime.h>

#define KK 64
#define TT 1024
#define BB 256
#define START_TAG 0

__device__ __forceinline__ float lane_bcast(float v, int lane) {
    return __int_as_float(__builtin_amdgcn_readlane(__float_as_int(v), lane));
}

// gfx950 two-register half-wave / row-pair swaps (VALU lane-crossing ops,
// not DS). Both operands are read-write (the registers exchange lanes).
#define SWAPL32(X, Y) asm volatile("v_permlane32_swap_b32 %0, %1" : "+v"(X), "+v"(Y));
#define SWAPL16(X, Y) asm volatile("v_permlane16_swap_b32 %0, %1" : "+v"(X), "+v"(Y));

// DPP row-rotate (within each 16-lane row) on src0. VOLATILE + hand
// interleaving: r6 ran 64 DPP fmacs on 4 chains (dep distance 4) at
// 8 cyc/inst — DPP latency ~10-16 cyc stalled every op, and non-volatile
// asm let the scheduler cluster same-chain ops. This version: 8 chains,
// dep distance 8, program order pinned.
#define RMOVI(D, S, K) \
    asm volatile("v_mov_b32 %0, %1 row_ror:" #K " row_mask:0xf bank_mask:0xf" \
        : "=v"(D) : "v"(S));
#define RMUL(D, S, K, E) \
    asm volatile("v_mul_f32 %0, %1, %2 row_ror:" #K " row_mask:0xf bank_mask:0xf" \
        : "=v"(D) : "v"(S), "v"(E));
#define RFMA(D, S, K, E) \
    asm volatile("v_fmac_f32 %0, %1, %2 row_ror:" #K " row_mask:0xf bank_mask:0xf" \
        : "+v"(D) : "v"(S), "v"(E));

// Direction/semantics-proof et gather: the SAME permlane+row_ror network is
// run on the lane-id vector at setup; et is gathered at the resulting
// per-lane indices (r6-verified on HW, absmax 0.0).
#define GATHER(dst, src, K) { int x_; RMOVI(x_, src, K) dst = __expf(trow[x_]); }

#define PIN4(p,q,r,s) asm volatile("" : "+v"(p), "+v"(q), "+v"(r), "+v"(s));

// Two rotation levels (even K on chains c0-c3, odd K1 on c4-c7):
// 8 fmacs, every chain revisited at distance exactly 8.
#define FMA8(K, K1) \
    RFMA(c0, U,  K,  etA##K)  RFMA(c1, U2, K,  etB##K) \
    RFMA(c2, V,  K,  etC##K)  RFMA(c3, V2, K,  etD##K) \
    RFMA(c4, U,  K1, etA##K1) RFMA(c5, U2, K1, etB##K1) \
    RFMA(c6, V,  K1, etC##K1) RFMA(c7, V2, K1, etD##K1)

// One recurrence step — ~86 instructions, ZERO DS ops, zero barriers:
//  4 mov + 3 permlane swaps build {U,U2,V,V2} (the four 16-state blocks of
//  a at each lane position), 64 MACs via row_ror DPP on EIGHT chains
//  (first touch = mul), 7-add tree, scale + mask select (+ renorm /4 steps).
//  s_nop fences: VALU-write -> lane-crossing-read hazards around inline asm
//  are the programmer's responsibility.
#define DO_STEP(EFV, MKV, RN) { \
    float U = a, V = a; \
    asm volatile("s_nop 1" : "+v"(U), "+v"(V)); \
    SWAPL32(U, V) \
    float U2 = U, V2 = V; \
    asm volatile("s_nop 1" : "+v"(U), "+v"(U2), "+v"(V), "+v"(V2)); \
    SWAPL16(U, U2) \
    SWAPL16(V, V2) \
    asm volatile("s_nop 1" : "+v"(U), "+v"(U2), "+v"(V), "+v"(V2)); \
    float c0, c1, c2, c3, c4, c5, c6, c7; \
    c0 = U * etA0;  c1 = U2 * etB0;  c2 = V * etC0;  c3 = V2 * etD0; \
    RMUL(c4, U, 1, etA1) RMUL(c5, U2, 1, etB1) \
    RMUL(c6, V, 1, etC1) RMUL(c7, V2, 1, etD1) \
    FMA8(2, 3)   FMA8(4, 5)   FMA8(6, 7)   FMA8(8, 9) \
    FMA8(10, 11) FMA8(12, 13) FMA8(14, 15) \
    float d0 = c0 + c4, d1 = c1 + c5, d2 = c2 + c6, d3 = c3 + c7; \
    float s_ = (d0 + d1) + (d2 + d3); \
    float anew = s_ * (EFV); \
    a = ((MKV) != 0.0f) ? anew : a; \
    if (RN) { \
        float a1 = fmaxf(lane_bcast(a, 1), 1e-37f); \
        a *= __builtin_amdgcn_rcpf(a1); \
        offset += __logf(a1); \
    } \
}

// Forward algorithm in the probability domain. One wave per batch element;
// lane i owns state i. Evidence rounds 0-7: every schedule keeping LDS in
// the recurrence floors at ~530 cyc/step (write->read round-trip constant);
// pure-VALU r6 floored on DPP dep stalls (4 chains). This version removes
// both: no DS ops, 8 chains. Renorm once per 4 steps by a[1] (wave-uniform
// positive scale is exact via offset += log(scale)).
__global__ __launch_bounds__(64)
__attribute__((amdgpu_waves_per_eu(1, 1)))
void crf_forward_kernel(
    const float* __restrict__ feats,
    const float* __restrict__ trans,
    const float* __restrict__ masks,
    const int*   __restrict__ tags,
    float* __restrict__ out)
{
    const int b = blockIdx.x;
    const int i = threadIdx.x;

    const float* trow = trans + i * KK;

    // --- run the permutation network on lane ids (index vectors) ---
    int lid = i;
    asm volatile("s_nop 1" : "+v"(lid));
    int jU = lid, jV = lid;
    asm volatile("s_nop 1" : "+v"(jU), "+v"(jV));
    SWAPL32(jU, jV)
    int jU2 = jU, jV2 = jV;
    asm volatile("s_nop 1" : "+v"(jU), "+v"(jU2), "+v"(jV), "+v"(jV2));
    SWAPL16(jU, jU2)
    SWAPL16(jV, jV2)
    asm volatile("s_nop 1" : "+v"(jU), "+v"(jU2), "+v"(jV), "+v"(jV2));

    // --- gather et[chain][rot] = exp(trans[i][sigma_chain(ror_rot(i))]) ---
    float etA0, etA1, etA2, etA3, etA4, etA5, etA6, etA7,
          etA8, etA9, etA10, etA11, etA12, etA13, etA14, etA15;
    float etB0, etB1, etB2, etB3, etB4, etB5, etB6, etB7,
          etB8, etB9, etB10, etB11, etB12, etB13, etB14, etB15;
    float etC0, etC1, etC2, etC3, etC4, etC5, etC6, etC7,
          etC8, etC9, etC10, etC11, etC12, etC13, etC14, etC15;
    float etD0, etD1, etD2, etD3, etD4, etD5, etD6, etD7,
          etD8, etD9, etD10, etD11, etD12, etD13, etD14, etD15;
    etA0 = __expf(trow[jU]);  etB0 = __expf(trow[jU2]);
    etC0 = __expf(trow[jV]);  etD0 = __expf(trow[jV2]);
    GATHER(etA1, jU, 1)   GATHER(etA2, jU, 2)   GATHER(etA3, jU, 3)
    GATHER(etA4, jU, 4)   GATHER(etA5, jU, 5)   GATHER(etA6, jU, 6)
    GATHER(etA7, jU, 7)   GATHER(etA8, jU, 8)   GATHER(etA9, jU, 9)
    GATHER(etA10, jU, 10) GATHER(etA11, jU, 11) GATHER(etA12, jU, 12)
    GATHER(etA13, jU, 13) GATHER(etA14, jU, 14) GATHER(etA15, jU, 15)
    GATHER(etB1, jU2, 1)   GATHER(etB2, jU2, 2)   GATHER(etB3, jU2, 3)
    GATHER(etB4, jU2, 4)   GATHER(etB5, jU2, 5)   GATHER(etB6, jU2, 6)
    GATHER(etB7, jU2, 7)   GATHER(etB8, jU2, 8)   GATHER(etB9, jU2, 9)
    GATHER(etB10, jU2, 10) GATHER(etB11, jU2, 11) GATHER(etB12, jU2, 12)
    GATHER(etB13, jU2, 13) GATHER(etB14, jU2, 14) GATHER(etB15, jU2, 15)
    GATHER(etC1, jV, 1)   GATHER(etC2, jV, 2)   GATHER(etC3, jV, 3)
    GATHER(etC4, jV, 4)   GATHER(etC5, jV, 5)   GATHER(etC6, jV, 6)
    GATHER(etC7, jV, 7)   GATHER(etC8, jV, 8)   GATHER(etC9, jV, 9)
    GATHER(etC10, jV, 10) GATHER(etC11, jV, 11) GATHER(etC12, jV, 12)
    GATHER(etC13, jV, 13) GATHER(etC14, jV, 14) GATHER(etC15, jV, 15)
    GATHER(etD1, jV2, 1)   GATHER(etD2, jV2, 2)   GATHER(etD3, jV2, 3)
    GATHER(etD4, jV2, 4)   GATHER(etD5, jV2, 5)   GATHER(etD6, jV2, 6)
    GATHER(etD7, jV2, 7)   GATHER(etD8, jV2, 8)   GATHER(etD9, jV2, 9)
    GATHER(etD10, jV2, 10) GATHER(etD11, jV2, 11) GATHER(etD12, jV2, 12)
    GATHER(etD13, jV2, 13) GATHER(etD14, jV2, 14) GATHER(etD15, jV2, 15)

    PIN4(etA0, etA1, etA2, etA3)     PIN4(etA4, etA5, etA6, etA7)
    PIN4(etA8, etA9, etA10, etA11)   PIN4(etA12, etA13, etA14, etA15)
    PIN4(etB0, etB1, etB2, etB3)     PIN4(etB4, etB5, etB6, etB7)
    PIN4(etB8, etB9, etB10, etB11)   PIN4(etB12, etB13, etB14, etB15)
    PIN4(etC0, etC1, etC2, etC3)     PIN4(etC4, etC5, etC6, etC7)
    PIN4(etC8, etC9, etC10, etC11)   PIN4(etC12, etC13, etC14, etC15)
    PIN4(etD0, etD1, etD2, etD3)     PIN4(etD4, etD5, etD6, etD7)
    PIN4(etD8, etD9, etD10, etD11)   PIN4(etD12, etD13, etD14, etD15)

    float a = (i == START_TAG) ? 1.0f : 0.0f;  // exp(alpha0)
    float offset = 0.0f;                        // running log-scale

    const float* fb = feats + (size_t)b * TT * KK;
    const float* mb = masks + (size_t)b * TT;

    // prologue prefetch: steps t = 1..4
    float cf0 = fb[1 * KK + i], cf1 = fb[2 * KK + i];
    float cf2 = fb[3 * KK + i], cf3 = fb[4 * KK + i];
    float cm0 = mb[1], cm1 = mb[2], cm2 = mb[3], cm3 = mb[4];

    // groups t0 = 1,5,...,1021; last group's 4th step (t=1024) masked off
    for (int t0 = 1; t0 < TT; t0 += 4) {
        int p0 = (t0 + 4 < TT) ? t0 + 4 : TT - 1;
        int p1 = (t0 + 5 < TT) ? t0 + 5 : TT - 1;
        int p2 = (t0 + 6 < TT) ? t0 + 6 : TT - 1;
        int p3 = (t0 + 7 < TT) ? t0 + 7 : TT - 1;
        float nf0 = fb[p0 * KK + i], nf1 = fb[p1 * KK + i];
        float nf2 = fb[p2 * KK + i], nf3 = fb[p3 * KK + i];
        float nm0 = mb[p0], nm1 = mb[p1], nm2 = mb[p2], nm3 = mb[p3];

        // exp(feat): inputs prefetched a full group ago -> off critical path
        float ef0 = __expf(cf0), ef1 = __expf(cf1);
        float ef2 = __expf(cf2), ef3 = __expf(cf3);

        DO_STEP(ef0, cm0, 0)
        DO_STEP(ef1, cm1, 0)
        DO_STEP(ef2, cm2, 0)
        float m3 = (t0 + 3 < TT) ? cm3 : 0.0f;   // only last group clips
        DO_STEP(ef3, m3, 1)                       // renorm folded into step 4

        cf0 = nf0; cf1 = nf1; cf2 = nf2; cf3 = nf3;
        cm0 = nm0; cm1 = nm1; cm2 = nm2; cm3 = nm3;
    }

    // forward_score = offset + log(sum_j a_j)
    float s = a;
    #pragma unroll
    for (int off = 32; off >= 1; off >>= 1)
        s += __shfl_xor(s, off, 64);
    float fwd_score = offset + __logf(s);

    // ---- fused gold score: sum_t (trans[ct,pt] + feats[t,ct]) * mask[t] ----
    const int* tg = tags + b * TT;
    float g = 0.f;
    for (int t = 1 + i; t < TT; t += 64) {
        int ct = tg[t], pt = tg[t - 1];
        g += (trans[ct * KK + pt] + fb[t * KK + ct]) * mb[t];
    }
    #pragma unroll
    for (int off = 32; off >= 1; off >>= 1)
        g += __shfl_xor(g, off, 64);

    if (i == 0) atomicAdd(out, (fwd_score - g) * (1.0f / (float)BB));
}

extern "C" void kernel_launch(void* const* d_in, const int* in_sizes, int n_in,
                              void* d_out, int out_size, void* d_ws, size_t ws_size,
                              hipStream_t stream) {
    const float* feats = (const float*)d_in[0];
    const float* trans = (const float*)d_in[1];
    const int*   tags  = (const int*)d_in[2];
    const float* masks = (const float*)d_in[3];
    float* out = (float*)d_out;

    hipMemsetAsync(out, 0, sizeof(float), stream);  // atomicAdd accumulator
    crf_forward_kernel<<<BB, 64, 0, stream>>>(feats, trans, masks, tags, out);
}

// Round 9
// 301.198 us; speedup vs baseline: 1.1072x; 1.1072x over previous
//
#include <hip/hip_runtime.h>

#define KK 64
#define TT 1024
#define BB 256
#define START_TAG 0

typedef float v2f __attribute__((ext_vector_type(2)));
typedef float v4f __attribute__((ext_vector_type(4)));

__device__ __forceinline__ float lane_bcast(float v, int lane) {
    return __int_as_float(__builtin_amdgcn_readlane(__float_as_int(v), lane));
}

#define LOV(W) (__builtin_shufflevector((W), (W), 0, 1))
#define HIV(W) (__builtin_shufflevector((W), (W), 2, 3))

// readlane into a compiler-allocated SGPR (dependency tracked via constraint;
// volatile pins program order = the hand schedule)
#define RL1(SV, J) \
    asm volatile("v_readlane_b32 %0, %1, " #J : "=s"(SV) : "v"(av));
// VOP2 mul/fmac with SGPR src0 (exactly 1 scalar operand: architecturally legal)
#define MUL_S(C, SV, E) \
    asm volatile("v_mul_f32 %0, %1, %2" : "=v"(C) : "s"(SV), "v"(E));
#define FMAC_S(C, SV, E) \
    asm volatile("v_fmac_f32 %0, %1, %2" : "+v"(C) : "s"(SV), "v"(E));
// packed dual-fp32 (VOP3P)
#define PKMUL(D, S, E) \
    asm volatile("v_pk_mul_f32 %0, %1, %2" : "=v"(D) : "v"(S), "v"(E));
#define PKFMA(D, S, E) \
    asm volatile("v_pk_fma_f32 %0, %1, %2, %0" : "+v"(D) : "v"(S), "v"(E));
#define PKADD(D, X, Y) \
    asm volatile("v_pk_add_f32 %0, %1, %2" : "=v"(D) : "v"(X), "v"(Y));

#define PIN4(p,q,r,s) asm volatile("" : "+v"(p), "+v"(q), "+v"(r), "+v"(s));

// One recurrence step, two-pipe delivery:
//   DS pipe:  ds_write a[i], then 12x ds_read_b128 broadcast (j = 16..63);
//             same-wave DS ops retire in order, so the write is visible to
//             the reads with no wait.
//   VALU pipe (runs DURING the DS round trip): 16x v_readlane (j = 0..15)
//             into SGPRs + 16 fmac with sgpr src0 on 4 chains.
//   Then one lgkmcnt(0) + sched_barrier (rule #18) and 24 pk ops consume
//   the LDS half; tree, scale, optional mask select / renorm.
#define DO_STEP(EFV, HASM, MKV, RN) { \
    float av = a; \
    asm volatile("ds_write_b32 %0, %1" :: "v"(adW), "v"(av)); \
    v4f w0,w1,w2,w3,w4,w5,w6,w7,w8,w9,w10,w11; \
    asm volatile("ds_read_b128 %0, %1"            : "=v"(w0)  : "v"(adR)); \
    asm volatile("ds_read_b128 %0, %1 offset:16"  : "=v"(w1)  : "v"(adR)); \
    asm volatile("ds_read_b128 %0, %1 offset:32"  : "=v"(w2)  : "v"(adR)); \
    asm volatile("ds_read_b128 %0, %1 offset:48"  : "=v"(w3)  : "v"(adR)); \
    asm volatile("ds_read_b128 %0, %1 offset:64"  : "=v"(w4)  : "v"(adR)); \
    asm volatile("ds_read_b128 %0, %1 offset:80"  : "=v"(w5)  : "v"(adR)); \
    asm volatile("ds_read_b128 %0, %1 offset:96"  : "=v"(w6)  : "v"(adR)); \
    asm volatile("ds_read_b128 %0, %1 offset:112" : "=v"(w7)  : "v"(adR)); \
    asm volatile("ds_read_b128 %0, %1 offset:128" : "=v"(w8)  : "v"(adR)); \
    asm volatile("ds_read_b128 %0, %1 offset:144" : "=v"(w9)  : "v"(adR)); \
    asm volatile("ds_read_b128 %0, %1 offset:160" : "=v"(w10) : "v"(adR)); \
    asm volatile("ds_read_b128 %0, %1 offset:176" : "=v"(w11) : "v"(adR)); \
    int sj0,sj1,sj2,sj3,sj4,sj5,sj6,sj7,sj8,sj9,sj10,sj11,sj12,sj13,sj14,sj15; \
    RL1(sj0,0)   RL1(sj1,1)   RL1(sj2,2)   RL1(sj3,3) \
    RL1(sj4,4)   RL1(sj5,5)   RL1(sj6,6)   RL1(sj7,7) \
    RL1(sj8,8)   RL1(sj9,9)   RL1(sj10,10) RL1(sj11,11) \
    RL1(sj12,12) RL1(sj13,13) RL1(sj14,14) RL1(sj15,15) \
    float c0,c1,c2,c3; \
    MUL_S(c0,sj0,ets0)    MUL_S(c1,sj1,ets1)    MUL_S(c2,sj2,ets2)    MUL_S(c3,sj3,ets3) \
    FMAC_S(c0,sj4,ets4)   FMAC_S(c1,sj5,ets5)   FMAC_S(c2,sj6,ets6)   FMAC_S(c3,sj7,ets7) \
    FMAC_S(c0,sj8,ets8)   FMAC_S(c1,sj9,ets9)   FMAC_S(c2,sj10,ets10) FMAC_S(c3,sj11,ets11) \
    FMAC_S(c0,sj12,ets12) FMAC_S(c1,sj13,ets13) FMAC_S(c2,sj14,ets14) FMAC_S(c3,sj15,ets15) \
    asm volatile("s_waitcnt lgkmcnt(0)" ::: "memory"); \
    __builtin_amdgcn_sched_barrier(0); \
    v2f q0,q1,q2,q3; \
    PKMUL(q0, LOV(w0), etp0)   PKMUL(q1, HIV(w0), etp1) \
    PKMUL(q2, LOV(w1), etp2)   PKMUL(q3, HIV(w1), etp3) \
    PKFMA(q0, LOV(w2), etp4)   PKFMA(q1, HIV(w2), etp5) \
    PKFMA(q2, LOV(w3), etp6)   PKFMA(q3, HIV(w3), etp7) \
    PKFMA(q0, LOV(w4), etp8)   PKFMA(q1, HIV(w4), etp9) \
    PKFMA(q2, LOV(w5), etp10)  PKFMA(q3, HIV(w5), etp11) \
    PKFMA(q0, LOV(w6), etp12)  PKFMA(q1, HIV(w6), etp13) \
    PKFMA(q2, LOV(w7), etp14)  PKFMA(q3, HIV(w7), etp15) \
    PKFMA(q0, LOV(w8), etp16)  PKFMA(q1, HIV(w8), etp17) \
    PKFMA(q2, LOV(w9), etp18)  PKFMA(q3, HIV(w9), etp19) \
    PKFMA(q0, LOV(w10), etp20) PKFMA(q1, HIV(w10), etp21) \
    PKFMA(q2, LOV(w11), etp22) PKFMA(q3, HIV(w11), etp23) \
    v2f qA,qB,qC; \
    PKADD(qA,q0,q1) PKADD(qB,q2,q3) PKADD(qC,qA,qB) \
    float s_ = ((c0+c1)+(c2+c3)) + (qC.x+qC.y); \
    float anew = s_ * (EFV); \
    if (HASM) { a = ((MKV) != 0.0f) ? anew : a; } else { a = anew; } \
    if (RN) { \
        float a1 = fmaxf(lane_bcast(a, 1), 1e-37f); \
        a *= __builtin_amdgcn_rcpf(a1); \
        offset += __logf(a1); \
    } \
}

// Forward algorithm in the probability domain. One wave per batch element;
// lane i owns state i. Evidence r0-r8: single-wave delivery floors —
// LDS-only 530 (round-trip constant), DPP 600-645, swizzle 620, RL+fma 690.
// This version is the untested combination: both pipes at once (LDS carries
// 48 values in the background while readlane+fmac carry 16 on the VALU),
// plus an all-ones-mask fast path (bench masks are all 1.0; generic masked
// loop kept as fallback). Renorm once per 4 steps by a[1].
__global__ __launch_bounds__(64)
__attribute__((amdgpu_waves_per_eu(1, 1)))
void crf_forward_kernel(
    const float* __restrict__ feats,
    const float* __restrict__ trans,
    const float* __restrict__ masks,
    const int*   __restrict__ tags,
    float* __restrict__ out)
{
    const int b = blockIdx.x;
    const int i = threadIdx.x;

    __shared__ __align__(16) float abuf[KK];

    const float* trow = trans + i * KK;

    // RL half: scalar et for j = 0..15
    float ets0  = __expf(trow[0]),  ets1  = __expf(trow[1]);
    float ets2  = __expf(trow[2]),  ets3  = __expf(trow[3]);
    float ets4  = __expf(trow[4]),  ets5  = __expf(trow[5]);
    float ets6  = __expf(trow[6]),  ets7  = __expf(trow[7]);
    float ets8  = __expf(trow[8]),  ets9  = __expf(trow[9]);
    float ets10 = __expf(trow[10]), ets11 = __expf(trow[11]);
    float ets12 = __expf(trow[12]), ets13 = __expf(trow[13]);
    float ets14 = __expf(trow[14]), ets15 = __expf(trow[15]);
    // LDS half: v2f et pairs for j = 16..63 (pair p -> j = 16+2p, 17+2p)
#define DECLP(p) v2f etp##p = { __expf(trow[16 + 2*(p)]), __expf(trow[17 + 2*(p)]) };
    DECLP(0)  DECLP(1)  DECLP(2)  DECLP(3)  DECLP(4)  DECLP(5)
    DECLP(6)  DECLP(7)  DECLP(8)  DECLP(9)  DECLP(10) DECLP(11)
    DECLP(12) DECLP(13) DECLP(14) DECLP(15) DECLP(16) DECLP(17)
    DECLP(18) DECLP(19) DECLP(20) DECLP(21) DECLP(22) DECLP(23)

    PIN4(ets0, ets1, ets2, ets3)     PIN4(ets4, ets5, ets6, ets7)
    PIN4(ets8, ets9, ets10, ets11)   PIN4(ets12, ets13, ets14, ets15)
    PIN4(etp0, etp1, etp2, etp3)     PIN4(etp4, etp5, etp6, etp7)
    PIN4(etp8, etp9, etp10, etp11)   PIN4(etp12, etp13, etp14, etp15)
    PIN4(etp16, etp17, etp18, etp19) PIN4(etp20, etp21, etp22, etp23)

    // DS byte addresses (generic LDS pointer low 32 bits = DS offset)
    unsigned lds_base = (unsigned)(uintptr_t)(void*)abuf;
    unsigned adW = lds_base + ((unsigned)i << 2);
    unsigned adR = lds_base + 64u;   // byte address of a[16]

    float a = (i == START_TAG) ? 1.0f : 0.0f;  // exp(alpha0)
    float offset = 0.0f;                        // running log-scale

    const float* fb = feats + (size_t)b * TT * KK;
    const float* mb = masks + (size_t)b * TT;

    // all-ones mask detection (bench: masks are all 1.0)
    int okm = 1;
    for (int t = 1 + i; t < TT; t += 64) okm &= (mb[t] == 1.0f) ? 1 : 0;
    bool allones = (__ballot(okm != 0) == ~0ull);

    if (allones) {
        // ---- fast path: no mask handling in the hot loop ----
        // groups t0 = 1,5,...,1017 (steps 1..1020), then 3 tail steps.
        float cf0 = fb[1 * KK + i], cf1 = fb[2 * KK + i];
        float cf2 = fb[3 * KK + i], cf3 = fb[4 * KK + i];
        for (int t0 = 1; t0 + 3 < TT; t0 += 4) {
            int p0 = (t0 + 4 < TT) ? t0 + 4 : TT - 1;
            int p1 = (t0 + 5 < TT) ? t0 + 5 : TT - 1;
            int p2 = (t0 + 6 < TT) ? t0 + 6 : TT - 1;
            int p3 = (t0 + 7 < TT) ? t0 + 7 : TT - 1;
            float nf0 = fb[p0 * KK + i], nf1 = fb[p1 * KK + i];
            float nf2 = fb[p2 * KK + i], nf3 = fb[p3 * KK + i];
            // exp(feat): inputs prefetched a full group ago -> off crit path
            float ef0 = __expf(cf0), ef1 = __expf(cf1);
            float ef2 = __expf(cf2), ef3 = __expf(cf3);
            DO_STEP(ef0, 0, 0.0f, 0)
            DO_STEP(ef1, 0, 0.0f, 0)
            DO_STEP(ef2, 0, 0.0f, 0)
            DO_STEP(ef3, 0, 0.0f, 1)   // renorm folded into 4th step
            cf0 = nf0; cf1 = nf1; cf2 = nf2; cf3 = nf3;
        }
        // tail steps t = 1021..1023 (already prefetched into cf0..cf2);
        // <= 3 steps since last renorm -> no overflow risk
        float ef0 = __expf(cf0), ef1 = __expf(cf1), ef2 = __expf(cf2);
        DO_STEP(ef0, 0, 0.0f, 0)
        DO_STEP(ef1, 0, 0.0f, 0)
        DO_STEP(ef2, 0, 0.0f, 0)
    } else {
        // ---- generic path: per-step mask select (r4-verified structure) ----
        float cf0 = fb[1 * KK + i], cf1 = fb[2 * KK + i];
        float cf2 = fb[3 * KK + i], cf3 = fb[4 * KK + i];
        float cm0 = mb[1], cm1 = mb[2], cm2 = mb[3], cm3 = mb[4];
        for (int t0 = 1; t0 < TT; t0 += 4) {
            int p0 = (t0 + 4 < TT) ? t0 + 4 : TT - 1;
            int p1 = (t0 + 5 < TT) ? t0 + 5 : TT - 1;
            int p2 = (t0 + 6 < TT) ? t0 + 6 : TT - 1;
            int p3 = (t0 + 7 < TT) ? t0 + 7 : TT - 1;
            float nf0 = fb[p0 * KK + i], nf1 = fb[p1 * KK + i];
            float nf2 = fb[p2 * KK + i], nf3 = fb[p3 * KK + i];
            float nm0 = mb[p0], nm1 = mb[p1], nm2 = mb[p2], nm3 = mb[p3];
            float ef0 = __expf(cf0), ef1 = __expf(cf1);
            float ef2 = __expf(cf2), ef3 = __expf(cf3);
            DO_STEP(ef0, 1, cm0, 0)
            DO_STEP(ef1, 1, cm1, 0)
            DO_STEP(ef2, 1, cm2, 0)
            float m3 = (t0 + 3 < TT) ? cm3 : 0.0f;   // last group clips t=1024
            DO_STEP(ef3, 1, m3, 1)
            cf0 = nf0; cf1 = nf1; cf2 = nf2; cf3 = nf3;
            cm0 = nm0; cm1 = nm1; cm2 = nm2; cm3 = nm3;
        }
    }

    // forward_score = offset + log(sum_j a_j)
    float s = a;
    #pragma unroll
    for (int off = 32; off >= 1; off >>= 1)
        s += __shfl_xor(s, off, 64);
    float fwd_score = offset + __logf(s);

    // ---- fused gold score: sum_t (trans[ct,pt] + feats[t,ct]) * mask[t] ----
    const int* tg = tags + b * TT;
    float g = 0.f;
    for (int t = 1 + i; t < TT; t += 64) {
        int ct = tg[t], pt = tg[t - 1];
        g += (trans[ct * KK + pt] + fb[t * KK + ct]) * mb[t];
    }
    #pragma unroll
    for (int off = 32; off >= 1; off >>= 1)
        g += __shfl_xor(g, off, 64);

    if (i == 0) atomicAdd(out, (fwd_score - g) * (1.0f / (float)BB));
}

extern "C" void kernel_launch(void* const* d_in, const int* in_sizes, int n_in,
                              void* d_out, int out_size, void* d_ws, size_t ws_size,
                              hipStream_t stream) {
    const float* feats = (const float*)d_in[0];
    const float* trans = (const float*)d_in[1];
    const int*   tags  = (const int*)d_in[2];
    const float* masks = (const float*)d_in[3];
    float* out = (float*)d_out;

    hipMemsetAsync(out, 0, sizeof(float), stream);  // atomicAdd accumulator
    crf_forward_kernel<<<BB, 64, 0, stream>>>(feats, trans, masks, tags, out);
}